// Round 1
// baseline (1012.867 us; speedup 1.0000x reference)
//
#include <hip/hip_runtime.h>

// WeatherLSTM on MI355X.
// Structure: 128 persistent wgs x 512 threads; each wg owns 16 batch rows for
// all 279 recurrence steps. Per step: M=16,N=768,K=288 bf16 MFMA GEMM
// (f-gate dropped; x@Wx folded in as 9th K-tile), activations on VALU,
// h double-buffered in LDS (1 barrier/step). Weights pre-packed into MFMA
// B-fragment layout in d_ws (432 KB + bias), streamed from L2 each step.

typedef short bf16x8 __attribute__((ext_vector_type(8)));
typedef float f32x4 __attribute__((ext_vector_type(4)));

#define T_ENC 256
#define N_DEC 23
#define NSTEP 279
#define HSTR 296  // LDS h row stride in shorts (592 B: 16B-aligned, 2-way-bank free)
#define WPACK_SHORTS (48 * 9 * 512)  // 48 N-tiles x 9 K-tiles x 512 bf16

__device__ __forceinline__ short f2bf(float f) {
  unsigned u = __float_as_uint(f);
  u = (u + 0x7fffu + ((u >> 16) & 1u)) >> 16;  // RNE
  return (short)u;
}
__device__ __forceinline__ float bf2f(short s) {
  return __uint_as_float(((unsigned)(unsigned short)s) << 16);
}

#if __has_builtin(__builtin_amdgcn_rcpf)
#define RCPF(x) __builtin_amdgcn_rcpf(x)
#else
#define RCPF(x) (1.0f / (x))
#endif

__device__ __forceinline__ float sigm(float x) { return RCPF(1.0f + __expf(-x)); }
__device__ __forceinline__ float tanhf_fast(float x) {
  return 1.0f - 2.0f * RCPF(__expf(2.0f * x) + 1.0f);
}

// Pack [Wh;Wx;0] (3 gates only: i|o|g) into B-fragment layout:
// lane l elem e of tile (n_tile,kt) = W[k = 32*kt + 8*(l>>4) + e][col(n_tile, l&15)].
// Same k-convention as the A-side ds_read_b128, so layout questions cancel.
__global__ void pack_kernel(const float* __restrict__ Wx, const float* __restrict__ Wh,
                            const float* __restrict__ b, short* __restrict__ Wpack,
                            float* __restrict__ bpack) {
  int tau = blockIdx.x;  // 0..431 = n_tile*9 + kt
  int l = threadIdx.x;   // 0..63
  int n_tile = tau / 9, kt = tau % 9;
  int w = n_tile / 6, t = n_tile % 6;   // wave w owns 6 tiles: t=0,1 i; 2,3 o; 4,5 g
  int gate = t >> 1, loc = t & 1;
  int base = (gate == 0) ? 0 : (gate == 1 ? 512 : 768);  // orig order [i|f|o|c], f dropped
  int c = l & 15, q = l >> 4;
  int oc = base + w * 32 + loc * 16 + c;
  bf16x8 v;
#pragma unroll
  for (int e = 0; e < 8; ++e) {
    int k = kt * 32 + q * 8 + e;
    float f;
    if (k < 256)      f = Wh[k * 1024 + oc];
    else if (k < 264) f = Wx[(k - 256) * 1024 + oc];
    else              f = 0.0f;
    v[e] = f2bf(f);
  }
  ((bf16x8*)Wpack)[tau * 64 + l] = v;
  if (kt == 0 && q == 0) bpack[n_tile * 16 + c] = b[oc];
}

__global__ __launch_bounds__(512, 2) void lstm_kernel(
    const float* __restrict__ inputs0, const float* __restrict__ inputs1,
    const float* __restrict__ Wy, const float* __restrict__ by,
    const float* __restrict__ dec_w, const float* __restrict__ dec_b,
    const short* __restrict__ Wpack, const float* __restrict__ bpack,
    float* __restrict__ out) {
  __shared__ short hbuf[2][16 * HSTR];  // double-buffered [m=16][k=288(+pad)] bf16
  __shared__ float Wy_lds[256];
  __shared__ float ypart[256];

  const int tid = threadIdx.x;
  const int wg = blockIdx.x;   // 0..127, batch rows wg*16..wg*16+15
  const int lane = tid & 63;
  const int w = tid >> 6;      // wave 0..7, owns gate cols for h-cols [32w,32w+32)
  const int q = lane >> 4;
  const int c = lane & 15;

  // zero both h buffers (h region, x region, zero-pad region)
  short* hz = &hbuf[0][0];
  for (int i = tid; i < 2 * 16 * HSTR; i += 512) hz[i] = 0;
  if (tid < 256) Wy_lds[tid] = Wy[tid];
  if (tid < 128) {  // stage x(step 0)
    int m = tid & 15, kk = tid >> 4;
    hbuf[0][m * HSTR + 256 + kk] = f2bf(inputs0[((wg * 16 + m) * 256 + 0) * 8 + kk]);
  }
  float bias[6];
#pragma unroll
  for (int t = 0; t < 6; ++t) bias[t] = bpack[w * 96 + t * 16 + c];
  const float byv = by[0];
  __syncthreads();

  const bf16x8* wp = (const bf16x8*)Wpack;
  const int tilebase = w * 54;  // wave's first tile (6 N-tiles x 9 K-tiles)

  for (int s = 0; s < NSTEP; ++s) {
    const short* hc = &hbuf[s & 1][0];
    short* hn = &hbuf[(s + 1) & 1][0];

    // A-fragments: lane holds h[m=c][k = 32*kt + 8*q + e] (one ds_read_b128 each)
    bf16x8 A[9];
#pragma unroll
    for (int kt = 0; kt < 9; ++kt)
      A[kt] = *(const bf16x8*)(hc + c * HSTR + kt * 32 + q * 8);

    f32x4 acc[6];
    bf16x8 Bb[2][9];
#pragma unroll
    for (int kt = 0; kt < 9; ++kt) Bb[0][kt] = wp[(tilebase + kt) * 64 + lane];
#pragma unroll
    for (int t = 0; t < 6; ++t) {
      if (t < 5) {
#pragma unroll
        for (int kt = 0; kt < 9; ++kt)
          Bb[(t + 1) & 1][kt] = wp[(tilebase + (t + 1) * 9 + kt) * 64 + lane];
      }
      f32x4 a;
      a[0] = bias[t]; a[1] = bias[t]; a[2] = bias[t]; a[3] = bias[t];
#pragma unroll
      for (int kt = 0; kt < 9; ++kt)
        a = __builtin_amdgcn_mfma_f32_16x16x32_bf16(A[kt], Bb[t & 1][kt], a, 0, 0, 0);
      acc[t] = a;
    }

    // prefetch x for step s+1 (encoder: inputs0; decoder: x1*dec_w+dec_b)
    float xv = 0.0f;
    const bool do_x = (tid < 128) && (s + 1 < NSTEP);
    if (do_x) {
      int m = tid & 15, kk = tid >> 4;
      int sn = s + 1;
      if (sn < T_ENC) {
        xv = inputs0[((wg * 16 + m) * 256 + sn) * 8 + kk];
      } else {
        int d = sn - T_ENC;
        xv = inputs1[(wg * 16 + m) * N_DEC + d] * dec_w[d * 8 + kk] + dec_b[d * 8 + kk];
      }
    }

    // activations: h_next = sig(o)*tanh(sig(i)*tanh(g)); D-layout row=(4q+r), col=c
#pragma unroll
    for (int p = 0; p < 2; ++p) {
      f32x4 iv = acc[p], ov = acc[2 + p], gv = acc[4 + p];
#pragma unroll
      for (int r = 0; r < 4; ++r) {
        float ii = sigm(iv[r]);
        float oo = sigm(ov[r]);
        float gg = tanhf_fast(gv[r]);
        float h = oo * tanhf_fast(ii * gg);
        hn[(4 * q + r) * HSTR + (w * 32 + p * 16 + c)] = f2bf(h);
      }
    }
    if (do_x) {
      int m = tid & 15, kk = tid >> 4;
      hn[m * HSTR + 256 + kk] = f2bf(xv);
    }
    __syncthreads();

    // y = h @ Wy + by at encoder end (col 0) and every decoder step (cols 1..23)
    if (s >= T_ENC - 1) {
      if (tid < 256) {
        int m = tid & 15, kq = tid >> 4;
        float part = 0.0f;
#pragma unroll
        for (int j = 0; j < 16; ++j)
          part += bf2f(hn[m * HSTR + kq * 16 + j]) * Wy_lds[kq * 16 + j];
        ypart[tid] = part;
      }
      __syncthreads();
      if (tid < 16) {
        float y = byv;
#pragma unroll
        for (int kq = 0; kq < 16; ++kq) y += ypart[kq * 16 + tid];
        out[(wg * 16 + tid) * 24 + (s - (T_ENC - 1))] = y;
      }
      // ypart reuse protected by next step's main barrier
    }
  }
}

extern "C" void kernel_launch(void* const* d_in, const int* in_sizes, int n_in,
                              void* d_out, int out_size, void* d_ws, size_t ws_size,
                              hipStream_t stream) {
  const float* inputs0 = (const float*)d_in[0];
  const float* inputs1 = (const float*)d_in[1];
  const float* Wx      = (const float*)d_in[2];
  const float* Wh      = (const float*)d_in[3];
  const float* b       = (const float*)d_in[4];
  const float* Wy      = (const float*)d_in[5];
  const float* by      = (const float*)d_in[6];
  const float* dec_w   = (const float*)d_in[7];
  const float* dec_b   = (const float*)d_in[8];

  short* Wpack = (short*)d_ws;                                   // 442368 B
  float* bpack = (float*)((char*)d_ws + WPACK_SHORTS * 2);       // + 3072 B

  pack_kernel<<<dim3(48 * 9), dim3(64), 0, stream>>>(Wx, Wh, b, Wpack, bpack);
  lstm_kernel<<<dim3(128), dim3(512), 0, stream>>>(
      inputs0, inputs1, Wy, by, dec_w, dec_b, Wpack, bpack, (float*)d_out);
}

// Round 2
// 529.961 us; speedup vs baseline: 1.9112x; 1.9112x over previous
//
#include <hip/hip_runtime.h>

// WeatherLSTM on MI355X — round 2: weight-resident design.
// 128 wgs x 512 threads; each wg owns 16 batch rows for all 279 steps.
// Per step: M=16,N=768,K=288 bf16 MFMA GEMM (f-gate dropped, x folded as
// 9th K-tile). Weights NO LONGER streamed from L2: each wave holds 37 of
// its 54 B-tiles in VGPRs (148 regs) and 17 in LDS (136 KB/wg), loaded once.
// h single-buffered in LDS (2 barriers/step).

typedef short bf16x8 __attribute__((ext_vector_type(8)));
typedef float f32x4 __attribute__((ext_vector_type(4)));

#define T_ENC 256
#define N_DEC 23
#define NSTEP 279
#define HSTR 296           // LDS h row stride in shorts (592 B)
#define REG_T 37           // B-tiles per wave in VGPRs
#define LDS_T 17           // B-tiles per wave in LDS
#define WPACK_SHORTS (48 * 9 * 512)

__device__ __forceinline__ short f2bf(float f) {
  unsigned u = __float_as_uint(f);
  u = (u + 0x7fffu + ((u >> 16) & 1u)) >> 16;  // RNE
  return (short)u;
}
__device__ __forceinline__ float bf2f(short s) {
  return __uint_as_float(((unsigned)(unsigned short)s) << 16);
}

#if __has_builtin(__builtin_amdgcn_rcpf)
#define RCPF(x) __builtin_amdgcn_rcpf(x)
#else
#define RCPF(x) (1.0f / (x))
#endif

__device__ __forceinline__ float sigm(float x) { return RCPF(1.0f + __expf(-x)); }
__device__ __forceinline__ float tanhf_fast(float x) {
  return 1.0f - 2.0f * RCPF(__expf(2.0f * x) + 1.0f);
}

// Pack [Wh;Wx;0] (3 gates: i|o|g) into B-fragment layout (unchanged from r1).
__global__ void pack_kernel(const float* __restrict__ Wx, const float* __restrict__ Wh,
                            const float* __restrict__ b, short* __restrict__ Wpack,
                            float* __restrict__ bpack) {
  int tau = blockIdx.x;  // 0..431 = n_tile*9 + kt
  int l = threadIdx.x;
  int n_tile = tau / 9, kt = tau % 9;
  int w = n_tile / 6, t = n_tile % 6;
  int gate = t >> 1, loc = t & 1;
  int base = (gate == 0) ? 0 : (gate == 1 ? 512 : 768);
  int c = l & 15, q = l >> 4;
  int oc = base + w * 32 + loc * 16 + c;
  bf16x8 v;
#pragma unroll
  for (int e = 0; e < 8; ++e) {
    int k = kt * 32 + q * 8 + e;
    float f;
    if (k < 256)      f = Wh[k * 1024 + oc];
    else if (k < 264) f = Wx[(k - 256) * 1024 + oc];
    else              f = 0.0f;
    v[e] = f2bf(f);
  }
  ((bf16x8*)Wpack)[tau * 64 + l] = v;
  if (kt == 0 && q == 0) bpack[n_tile * 16 + c] = b[oc];
}

__global__ __launch_bounds__(512, 2) void lstm_kernel(
    const float* __restrict__ inputs0, const float* __restrict__ inputs1,
    const float* __restrict__ Wy, const float* __restrict__ by,
    const float* __restrict__ dec_w, const float* __restrict__ dec_b,
    const short* __restrict__ Wpack, const float* __restrict__ bpack,
    float* __restrict__ out) {
  __shared__ short B_lds[8 * LDS_T * 512];  // 139264 B, read-only after preload
  __shared__ short hbuf[16 * HSTR];         // 9472 B, single-buffered
  __shared__ float Wy_lds[256];
  __shared__ float ypart[256];

  const int tid = threadIdx.x;
  const int wg = blockIdx.x;
  const int lane = tid & 63;
  const int w = tid >> 6;      // wave 0..7
  const int q = lane >> 4;
  const int c = lane & 15;

  const bf16x8* wp = (const bf16x8*)Wpack;

  // ---- persistent register weights: 37 tiles (r = t*9+kt, r<37) ----
  bf16x8 Breg[REG_T];
#pragma unroll
  for (int r = 0; r < REG_T; ++r) Breg[r] = wp[(w * 54 + r) * 64 + lane];

  // ---- LDS weights: tiles r = 37..53 -> j = 0..16 ----
  for (int j = 0; j < LDS_T; ++j) {
    bf16x8 v = wp[(w * 54 + REG_T + j) * 64 + lane];
    *(bf16x8*)(B_lds + (w * LDS_T + j) * 512 + lane * 8) = v;
  }

  // zero h buffer (incl. x region and zero-pad tail)
  for (int i = tid; i < 16 * HSTR; i += 512) hbuf[i] = 0;
  if (tid < 256) Wy_lds[tid] = Wy[tid];
  __syncthreads();  // zero-init complete before x0 staging (fixes r1 latent race)

  if (tid < 128) {  // stage x(step 0), coalesced: row = tid>>3, kk = tid&7
    int m = tid >> 3, kk = tid & 7;
    hbuf[m * HSTR + 256 + kk] = f2bf(inputs0[((wg * 16 + m) * 256 + 0) * 8 + kk]);
  }
  float bias[6];
#pragma unroll
  for (int t = 0; t < 6; ++t) bias[t] = bpack[w * 96 + t * 16 + c];
  const float byv = by[0];
  __syncthreads();

#define LDSB(j) (*(const bf16x8*)(B_lds + (w * LDS_T + (j)) * 512 + lane * 8))

  for (int s = 0; s < NSTEP; ++s) {
    // [1] A-fragments from h (needs h(s): guaranteed by trailing barrier)
    bf16x8 A[9];
#pragma unroll
    for (int kt = 0; kt < 9; ++kt)
      A[kt] = *(const bf16x8*)(hbuf + c * HSTR + kt * 32 + q * 8);

    __syncthreads();  // [2] all A-reads done before anyone writes h(s+1)

    // x prefetch for s+1 (issued early, consumed after MFMAs)
    float xv = 0.0f;
    const bool do_x = (tid < 128) && (s + 1 < NSTEP);
    const int xm = tid >> 3, xk = tid & 7;
    if (do_x) {
      int sn = s + 1;
      if (sn < T_ENC) {
        xv = inputs0[((wg * 16 + xm) * 256 + sn) * 8 + xk];
      } else {
        int d = sn - T_ENC;
        xv = inputs1[(wg * 16 + xm) * N_DEC + d] * dec_w[d * 8 + xk] + dec_b[d * 8 + xk];
      }
    }

    // [3] MFMAs: 6 N-tiles x 9 K-tiles; B from regs (r<37) or LDS (r>=37)
    f32x4 acc[6];
#pragma unroll
    for (int t = 0; t < 6; ++t) {
      f32x4 a; a[0] = bias[t]; a[1] = bias[t]; a[2] = bias[t]; a[3] = bias[t];
      acc[t] = a;
    }
#pragma unroll
    for (int t = 0; t < 4; ++t)
#pragma unroll
      for (int kt = 0; kt < 9; ++kt)
        acc[t] = __builtin_amdgcn_mfma_f32_16x16x32_bf16(A[kt], Breg[t * 9 + kt], acc[t], 0, 0, 0);
    acc[4] = __builtin_amdgcn_mfma_f32_16x16x32_bf16(A[0], Breg[36], acc[4], 0, 0, 0);
#pragma unroll
    for (int j = 0; j < LDS_T; ++j) {
      const int t = (j < 8) ? 4 : 5;
      const int kt = (j < 8) ? (j + 1) : (j - 8);
      acc[t] = __builtin_amdgcn_mfma_f32_16x16x32_bf16(A[kt], LDSB(j), acc[t], 0, 0, 0);
    }

    // [4] activations + h(s+1)/x(s+1) writes; D-layout row=(4q+r), col=c
#pragma unroll
    for (int p = 0; p < 2; ++p) {
      f32x4 iv = acc[p], ov = acc[2 + p], gv = acc[4 + p];
#pragma unroll
      for (int r = 0; r < 4; ++r) {
        float ii = sigm(iv[r]);
        float oo = sigm(ov[r]);
        float gg = tanhf_fast(gv[r]);
        float h = oo * tanhf_fast(ii * gg);
        hbuf[(4 * q + r) * HSTR + (w * 32 + p * 16 + c)] = f2bf(h);
      }
    }
    if (do_x) hbuf[xm * HSTR + 256 + xk] = f2bf(xv);
    __syncthreads();  // [5] h(s+1) visible

    // [6] y = h @ Wy + by (encoder end + every decoder step)
    if (s >= T_ENC - 1) {
      if (tid < 256) {
        int m = tid & 15, kq = tid >> 4;
        float part = 0.0f;
#pragma unroll
        for (int j = 0; j < 16; ++j)
          part += bf2f(hbuf[m * HSTR + kq * 16 + j]) * Wy_lds[kq * 16 + j];
        ypart[tid] = part;
      }
      __syncthreads();
      if (tid < 16) {
        float y = byv;
#pragma unroll
        for (int kq = 0; kq < 16; ++kq) y += ypart[kq * 16 + tid];
        out[(wg * 16 + tid) * 24 + (s - (T_ENC - 1))] = y;
      }
      // ypart reuse protected by next step's [2] barrier
    }
  }
}

extern "C" void kernel_launch(void* const* d_in, const int* in_sizes, int n_in,
                              void* d_out, int out_size, void* d_ws, size_t ws_size,
                              hipStream_t stream) {
  const float* inputs0 = (const float*)d_in[0];
  const float* inputs1 = (const float*)d_in[1];
  const float* Wx      = (const float*)d_in[2];
  const float* Wh      = (const float*)d_in[3];
  const float* b       = (const float*)d_in[4];
  const float* Wy      = (const float*)d_in[5];
  const float* by      = (const float*)d_in[6];
  const float* dec_w   = (const float*)d_in[7];
  const float* dec_b   = (const float*)d_in[8];

  short* Wpack = (short*)d_ws;
  float* bpack = (float*)((char*)d_ws + WPACK_SHORTS * 2);

  pack_kernel<<<dim3(48 * 9), dim3(64), 0, stream>>>(Wx, Wh, b, Wpack, bpack);
  lstm_kernel<<<dim3(128), dim3(512), 0, stream>>>(
      inputs0, inputs1, Wy, by, dec_w, dec_b, Wpack, bpack, (float*)d_out);
}

// Round 4
// 424.968 us; speedup vs baseline: 2.3834x; 1.2471x over previous
//
#include <hip/hip_runtime.h>

// WeatherLSTM on MI355X — round 4.
// 256 wgs x 512 threads; each wg owns 8 batch rows for all 279 steps (all
// 256 CUs). Per step: M=16(8 used),N=768,K=288 bf16 MFMA GEMM; f-gate
// dropped; x folded as 9th K-tile; bias folded via constant-1.0 A slot.
// A-row duplication (row = c&7) makes D rows 8-15 copies of 0-7, so ALL 64
// lanes hold valid gate values: lanes q<2 process p=0, q>=2 process p=1 —
// 4 outputs/lane, no cross-lane ops (r3's permlane swap removed).
// Per wave: 45 B-tiles in registers, 9 in LDS. LDS sized >80KB to force
// exactly 1 wg/CU.

typedef short bf16x8 __attribute__((ext_vector_type(8)));
typedef float f32x4 __attribute__((ext_vector_type(4)));

#define T_ENC 256
#define N_DEC 23
#define NSTEP 279
#define HSTR 296           // h row stride in shorts (592 B, 16B-aligned)
#define REG_T 45           // B-tiles per wave in VGPRs (t=0..4)
#define LDS_T 9            // B-tiles per wave in LDS (t=5)
#define WPACK_SHORTS (48 * 9 * 512)

__device__ __forceinline__ short f2bf(float f) {
  unsigned u = __float_as_uint(f);
  u = (u + 0x7fffu + ((u >> 16) & 1u)) >> 16;  // RNE
  return (short)u;
}
__device__ __forceinline__ float bf2f(short s) {
  return __uint_as_float(((unsigned)(unsigned short)s) << 16);
}

#if __has_builtin(__builtin_amdgcn_rcpf)
#define RCPF(x) __builtin_amdgcn_rcpf(x)
#else
#define RCPF(x) (1.0f / (x))
#endif

__device__ __forceinline__ float sigm(float x) { return RCPF(1.0f + __expf(-x)); }
__device__ __forceinline__ float tanhf_fast(float x) {
  return 1.0f - 2.0f * RCPF(__expf(2.0f * x) + 1.0f);
}

// Pack [Wh;Wx;bias;0] (3 gates: i|o|g) into B-fragment layout.
// k<256: Wh; 256..263: Wx; k==264: bias (pairs with constant-1.0 A slot).
__global__ void pack_kernel(const float* __restrict__ Wx, const float* __restrict__ Wh,
                            const float* __restrict__ b, short* __restrict__ Wpack) {
  int tau = blockIdx.x;  // 0..431 = n_tile*9 + kt
  int l = threadIdx.x;
  int n_tile = tau / 9, kt = tau % 9;
  int w = n_tile / 6, t = n_tile % 6;
  int gate = t >> 1, loc = t & 1;
  int base = (gate == 0) ? 0 : (gate == 1 ? 512 : 768);  // [i|f|o|c], f dropped
  int c = l & 15, q = l >> 4;
  int oc = base + w * 32 + loc * 16 + c;
  bf16x8 v;
#pragma unroll
  for (int e = 0; e < 8; ++e) {
    int k = kt * 32 + q * 8 + e;
    float f;
    if (k < 256)       f = Wh[k * 1024 + oc];
    else if (k < 264)  f = Wx[(k - 256) * 1024 + oc];
    else if (k == 264) f = b[oc];
    else               f = 0.0f;
    v[e] = f2bf(f);
  }
  ((bf16x8*)Wpack)[tau * 64 + l] = v;
}

__global__ __launch_bounds__(512, 2) void lstm_kernel(
    const float* __restrict__ inputs0, const float* __restrict__ inputs1,
    const float* __restrict__ Wy, const float* __restrict__ by,
    const float* __restrict__ dec_w, const float* __restrict__ dec_b,
    const short* __restrict__ Wpack, float* __restrict__ out) {
  __shared__ __align__(16) short B_lds[8 * LDS_T * 512];  // 73728 B
  __shared__ __align__(16) short hbuf[16 * HSTR];         // 9472 B (8 rows used)
  __shared__ float Wy_lds[256];
  __shared__ float ypart[128];
  // total ~84.7 KB -> exactly 1 wg/CU

  const int tid = threadIdx.x;
  const int wg = blockIdx.x;     // 0..255, batch rows wg*8 .. wg*8+7
  const int lane = tid & 63;
  const int w = tid >> 6;        // wave 0..7
  const int q = lane >> 4;       // 0..3
  const int c = lane & 15;

  const bf16x8* wp = (const bf16x8*)Wpack;

  // persistent register weights: tiles r = t*9+kt for t=0..4
  bf16x8 Breg[REG_T];
#pragma unroll
  for (int r = 0; r < REG_T; ++r) Breg[r] = wp[(w * 54 + r) * 64 + lane];
  // LDS weights: t=5, kt=0..8
#pragma unroll
  for (int j = 0; j < LDS_T; ++j) {
    bf16x8 v = wp[(w * 54 + REG_T + j) * 64 + lane];
    *(bf16x8*)(B_lds + (w * LDS_T + j) * 512 + lane * 8) = v;
  }

  for (int i = tid; i < 16 * HSTR; i += 512) hbuf[i] = 0;
  if (tid < 256) Wy_lds[tid] = Wy[tid];
  __syncthreads();  // zero-init complete before x0/bias staging

  if (tid < 64) {  // stage x(step 0)
    int m = tid >> 3, kk = tid & 7;
    hbuf[m * HSTR + 256 + kk] = f2bf(inputs0[((wg * 8 + m) * 256 + 0) * 8 + kk]);
  }
  if (tid < 8) hbuf[tid * HSTR + 264] = (short)0x3F80;  // constant 1.0 (bias slot)
  const float byv = by[0];
  __syncthreads();

  // A-frag read with row duplication: row = c&7 (rows 8-15 of D = rows 0-7)
#define RDA(kt) (*(const bf16x8*)(hbuf + (c & 7) * HSTR + (kt) * 32 + q * 8))
#define LDSB(j) (*(const bf16x8*)(B_lds + (w * LDS_T + (j)) * 512 + lane * 8))

  for (int s = 0; s < NSTEP; ++s) {
    // x prefetch for s+1 (global load overlaps MFMA; consumed after barrier)
    float xv = 0.0f;
    const bool do_x = (tid < 64) && (s + 1 < NSTEP);
    const int xm = tid >> 3, xk = tid & 7;
    if (do_x) {
      int sn = s + 1;
      if (sn < T_ENC) {
        xv = inputs0[((wg * 8 + xm) * 256 + sn) * 8 + xk];
      } else {
        int d = sn - T_ENC;
        xv = inputs1[(wg * 8 + xm) * N_DEC + d] * dec_w[d * 8 + xk] + dec_b[d * 8 + xk];
      }
    }

    // MFMA loop: 54 MFMAs/wave; A through 3-deep rolling window
    bf16x8 A3[3];
    A3[0] = RDA(0); A3[1] = RDA(1); A3[2] = RDA(2);
    f32x4 acc[6];
#pragma unroll
    for (int t = 0; t < 6; ++t) { acc[t][0] = 0.f; acc[t][1] = 0.f; acc[t][2] = 0.f; acc[t][3] = 0.f; }
#pragma unroll
    for (int kt = 0; kt < 9; ++kt) {
      const bf16x8 a = A3[kt % 3];
#pragma unroll
      for (int t = 0; t < 5; ++t)
        acc[t] = __builtin_amdgcn_mfma_f32_16x16x32_bf16(a, Breg[t * 9 + kt], acc[t], 0, 0, 0);
      acc[5] = __builtin_amdgcn_mfma_f32_16x16x32_bf16(a, LDSB(kt), acc[5], 0, 0, 0);
      if (kt + 3 < 9) A3[kt % 3] = RDA(kt + 3);
    }
    __syncthreads();  // all A-reads done; h(s) free to overwrite

    // lane-split activations: q<2 -> p=0 block, q>=2 -> p=1 block (valid via
    // A-row duplication). Compile-time reg indices only; 12 cndmask selects.
    const int qh = q >> 1;
    const f32x4 vi = qh ? acc[1] : acc[0];
    const f32x4 vo = qh ? acc[3] : acc[2];
    const f32x4 vg = qh ? acc[5] : acc[4];
    const int row0 = (q & 1) * 4;
    const int colw = w * 32 + qh * 16 + c;
#pragma unroll
    for (int j = 0; j < 4; ++j) {
      float ii = sigm(vi[j]);
      float oo = sigm(vo[j]);
      float gg = tanhf_fast(vg[j]);
      float h = oo * tanhf_fast(ii * gg);
      hbuf[(row0 + j) * HSTR + colw] = f2bf(h);
    }
    if (do_x) hbuf[xm * HSTR + 256 + xk] = f2bf(xv);
    __syncthreads();  // h(s+1) visible

    // y = h @ Wy + by at encoder end (col 0) and every decoder step
    if (s >= T_ENC - 1) {
      if (tid < 128) {
        int m = tid & 7, kq = tid >> 3;
        const short* hp = hbuf + m * HSTR + kq * 16;
        bf16x8 h0 = *(const bf16x8*)(hp);
        bf16x8 h1 = *(const bf16x8*)(hp + 8);
        float part = 0.0f;
#pragma unroll
        for (int j = 0; j < 8; ++j) {
          part += bf2f(h0[j]) * Wy_lds[kq * 16 + j];
          part += bf2f(h1[j]) * Wy_lds[kq * 16 + 8 + j];
        }
        ypart[tid] = part;  // tid = kq*8 + m
      }
      __syncthreads();
      if (tid < 8) {
        float y = byv;
#pragma unroll
        for (int kq = 0; kq < 16; ++kq) y += ypart[kq * 8 + tid];
        out[(wg * 8 + tid) * 24 + (s - (T_ENC - 1))] = y;
      }
      // ypart reuse protected by next step's first barrier
    }
  }
}

extern "C" void kernel_launch(void* const* d_in, const int* in_sizes, int n_in,
                              void* d_out, int out_size, void* d_ws, size_t ws_size,
                              hipStream_t stream) {
  const float* inputs0 = (const float*)d_in[0];
  const float* inputs1 = (const float*)d_in[1];
  const float* Wx      = (const float*)d_in[2];
  const float* Wh      = (const float*)d_in[3];
  const float* b       = (const float*)d_in[4];
  const float* Wy      = (const float*)d_in[5];
  const float* by      = (const float*)d_in[6];
  const float* dec_w   = (const float*)d_in[7];
  const float* dec_b   = (const float*)d_in[8];

  short* Wpack = (short*)d_ws;

  pack_kernel<<<dim3(48 * 9), dim3(64), 0, stream>>>(Wx, Wh, b, Wpack);
  lstm_kernel<<<dim3(256), dim3(512), 0, stream>>>(
      inputs0, inputs1, Wy, by, dec_w, dec_b, Wpack, (float*)d_out);
}